// Round 8
// baseline (3881.481 us; speedup 1.0000x reference)
//
#include <hip/hip_runtime.h>
#include <hip/hip_bf16.h>
#include <stdint.h>

#define N_TOK 8192
#define DIM   2048
#define FDIM  4096
#define NEXP  8

// ---- ws layout (bytes) ---- peak use ~252 MB; round-1 proved ws >= 311 MB
#define XB_OFF   0ull                        // bf16 x  [8192][2048]   33,554,432
#define GH_OFF   33554432ull                 // bf16 G/h [18432][4096] 150,994,944
#define META_OFF 184549376ull
#define CNT_OFF   (META_OFF)                 // int[8]
#define EBASE_OFF (META_OFF + 64ull)         // int[8]
#define ELIST_OFF (META_OFF + 128ull)        // int[8][8192]
#define EWTS_OFF  (ELIST_OFF + 262144ull)    // f32[8][8192]
#define WB_OFF   185073920ull                // bf16 weight half-buffer, 67,108,864

typedef float f32x4 __attribute__((ext_vector_type(4)));
typedef short s16x8 __attribute__((ext_vector_type(8)));

__device__ __forceinline__ uint32_t pkbf(float a, float b) {
  uint32_t ua = __builtin_bit_cast(uint32_t, a) + 0x8000u;
  uint32_t ub = __builtin_bit_cast(uint32_t, b) + 0x8000u;
  return (ua >> 16) | (ub & 0xffff0000u);
}

__device__ __forceinline__ void gld16(const void* g, void* l) {
  __builtin_amdgcn_global_load_lds(
      (__attribute__((address_space(1))) void*)g,
      (__attribute__((address_space(3))) void*)l, 16, 0, 0);
}

__global__ void zero_out_k(float* out) {
  const size_t i = ((size_t)blockIdx.x * 256 + threadIdx.x) * 4;
  *(float4*)(out + i) = make_float4(0.f, 0.f, 0.f, 0.f);
}

__global__ void init_k(int* cnt) {
  if (threadIdx.x < NEXP) cnt[threadIdx.x] = 0;
}

__global__ void router_k(const float* __restrict__ x, const float* __restrict__ gw,
                         __hip_bfloat16* __restrict__ xb, int* __restrict__ cnt,
                         int* __restrict__ elist, float* __restrict__ ewts) {
  const int n = blockIdx.x;
  const int t = threadIdx.x;
  const float* xr = x + (size_t)n * DIM;
  const float4 v0 = *(const float4*)(xr + t * 8);
  const float4 v1 = *(const float4*)(xr + t * 8 + 4);
  uint4 u;
  u.x = pkbf(v0.x, v0.y); u.y = pkbf(v0.z, v0.w);
  u.z = pkbf(v1.x, v1.y); u.w = pkbf(v1.z, v1.w);
  *(uint4*)(xb + (size_t)n * DIM + t * 8) = u;

  float p[NEXP];
#pragma unroll
  for (int e = 0; e < NEXP; ++e) {
    const float* g = gw + e * DIM + t * 8;
    const float4 g0 = *(const float4*)g;
    const float4 g1 = *(const float4*)(g + 4);
    p[e] = v0.x * g0.x + v0.y * g0.y + v0.z * g0.z + v0.w * g0.w +
           v1.x * g1.x + v1.y * g1.y + v1.z * g1.z + v1.w * g1.w;
  }
#pragma unroll
  for (int off = 32; off >= 1; off >>= 1)
#pragma unroll
    for (int e = 0; e < NEXP; ++e) p[e] += __shfl_xor(p[e], off, 64);

  __shared__ float red[4][NEXP];
  const int lane = t & 63, wv = t >> 6;
  if (lane == 0) {
#pragma unroll
    for (int e = 0; e < NEXP; ++e) red[wv][e] = p[e];
  }
  __syncthreads();
  if (t == 0) {
    float l0 = -1e30f, l1 = -1e30f;
    int e0 = 0, e1 = 0;
#pragma unroll
    for (int e = 0; e < NEXP; ++e) {
      float v = red[0][e] + red[1][e] + red[2][e] + red[3][e];
      if (v > l0) { l1 = l0; e1 = e0; l0 = v; e0 = e; }
      else if (v > l1) { l1 = v; e1 = e; }
    }
    const float ed = expf(l1 - l0);
    const float inv = 1.f / (1.f + ed);
    int s0 = atomicAdd(cnt + e0, 1);
    elist[e0 * N_TOK + s0] = n;
    ewts[e0 * N_TOK + s0] = inv;
    int s1 = atomicAdd(cnt + e1, 1);
    elist[e1 * N_TOK + s1] = (int)((uint32_t)n | 0x80000000u);
    ewts[e1 * N_TOK + s1] = ed * inv;
  }
}

__global__ void scan_k(const int* __restrict__ cnt, int* __restrict__ ebase) {
  if (threadIdx.x == 0 && blockIdx.x == 0) {
    int b = 0;
    for (int e = 0; e < NEXP; ++e) { ebase[e] = b; b += (cnt[e] + 127) & ~127; }
  }
}

// convert rows [r0, r0+nrh) of each expert's [rtot][kd] fp32 matrix -> bf16 [e][nrh][kd]
__global__ void convW_k(const float* __restrict__ src, __hip_bfloat16* __restrict__ dst,
                        int r0, int nrh, int rtot, int kd) {
  const int cpr = kd / 8;
  const int total = NEXP * nrh * cpr;
  for (int i = blockIdx.x * blockDim.x + threadIdx.x; i < total;
       i += gridDim.x * blockDim.x) {
    const int e = i / (nrh * cpr);
    const int rem = i - e * nrh * cpr;
    const int lr = rem / cpr;
    const int c = rem - lr * cpr;
    const float* s = src + ((size_t)e * rtot + r0 + lr) * (size_t)kd + c * 8;
    const float4 a = *(const float4*)s;
    const float4 b = *(const float4*)(s + 4);
    uint4 u;
    u.x = pkbf(a.x, a.y); u.y = pkbf(a.z, a.w);
    u.z = pkbf(b.x, b.y); u.w = pkbf(b.z, b.w);
    *(uint4*)(dst + ((size_t)e * nrh + lr) * (size_t)kd + c * 8) = u;
  }
}

// ============================================================================
// 128x128 grouped GEMM (m97 structure), BK=32, 4 waves, 2-stage LDS dbuf,
// both operands bf16 via global_load_lds w=16, simple 2-barrier K-loop,
// compiler-scheduled. TIGHT LDS: A[2][8KB] @0, B[2][8KB] @16384 = 32KB total
// -> 5 blocks/CU (20 waves/CU); inter-block overlap hides the barrier drain
// (round-5 retry: that attempt wasted 2x LDS -> 2 blocks/CU).
// Swizzle (both-sides): row r slot s holds src granule s^((r>>1)&3);
// read-side XOR is a per-lane constant. 0 bank conflicts (round-5 verified).
// MODE 0: G = Xb@w1h^T -> Gh ; MODE 1: h = silu(Gh)*(Xb@w3h^T) -> Gh ;
// MODE 2: out += we * (h@w2h^T)  (atomicAdd, 2 commutative adds/elem).
// ============================================================================
template <int KD, int MODE>
__global__ __launch_bounds__(256, 5) void gemm128(
    const __hip_bfloat16* __restrict__ Asrc, const __hip_bfloat16* __restrict__ Bw,
    __hip_bfloat16* __restrict__ Gh, float* __restrict__ out,
    const int* __restrict__ cnt, const int* __restrict__ ebase,
    const int* __restrict__ elist, const float* __restrict__ ewts, int noff) {
  constexpr int NT = KD / 32;
  constexpr int NRH = (MODE == 2 ? 1024 : 2048);   // B rows per expert in half-buffer
  const int e = blockIdx.z;
  const int count = cnt[e];
  const int mt = blockIdx.x;
  if (mt * 128 >= count) return;
  const int n0 = noff + blockIdx.y * 128;

  __shared__ char lds[32768];
  const int tid = threadIdx.x;
  const int lane = tid & 63, wv = tid >> 6;
  const int wr = wv >> 1, wc = wv & 1;
  const int* lst = elist + e * N_TOK;
  const size_t hrow0 = (size_t)ebase[e] + (size_t)mt * 128;

  // ---- staging: thread covers granules {tid, tid+256} per operand.
  // granule gi: row = gi>>2, slot = gi&3, src granule = slot ^ ((row>>1)&3)
  size_t srcA[2], srcB[2];
  int ldsO[2];
#pragma unroll
  for (int i = 0; i < 2; ++i) {
    const int gi = tid + i * 256;
    const int r = gi >> 2;
    const int c = (gi & 3) ^ ((r >> 1) & 3);
    size_t ga;
    if (MODE == 2) {
      ga = hrow0 + r;
    } else {
      int idx = mt * 128 + r;
      if (idx >= count) idx = 0;
      ga = (size_t)(lst[idx] & 0x7fffffff);
    }
    srcA[i] = ga * (size_t)KD + c * 8;
    srcB[i] = ((size_t)e * NRH + (n0 - noff) + r) * (size_t)KD + c * 8;
    ldsO[i] = i * 4096 + wv * 1024;     // + lane*16 applied by HW
  }

  // ---- fragment read offsets (swizzle term is a per-lane constant; row steps
  // of 16 leave (r>>1)&3 unchanged)
  const int cq = lane >> 4;                       // k-granule
  const int rA = wr * 64 + (lane & 15);
  const int rB = wc * 64 + (lane & 15);
  const int aoff = rA * 64 + ((cq ^ ((rA >> 1) & 3)) << 4);
  const int boff = 16384 + rB * 64 + ((cq ^ ((rB >> 1) & 3)) << 4);

  f32x4 acc[4][4];
#pragma unroll
  for (int m = 0; m < 4; ++m)
#pragma unroll
    for (int n = 0; n < 4; ++n) acc[m][n] = {0.f, 0.f, 0.f, 0.f};

  auto stage = [&](int tt, int db) {
#pragma unroll
    for (int i = 0; i < 2; ++i)
      gld16(Asrc + srcA[i] + tt * 32, lds + db * 8192 + ldsO[i]);
#pragma unroll
    for (int i = 0; i < 2; ++i)
      gld16(Bw + srcB[i] + tt * 32, lds + 16384 + db * 8192 + ldsO[i]);
  };

  stage(0, 0);
  __syncthreads();

  for (int t = 0; t < NT; ++t) {
    const int db = t & 1;
    if (t + 1 < NT) stage(t + 1, db ^ 1);
    s16x8 Af[4], Bf[4];
#pragma unroll
    for (int m = 0; m < 4; ++m)
      Af[m] = *(const s16x8*)(lds + db * 8192 + aoff + m * 1024);
#pragma unroll
    for (int n = 0; n < 4; ++n)
      Bf[n] = *(const s16x8*)(lds + db * 8192 + boff + n * 1024);
#pragma unroll
    for (int m = 0; m < 4; ++m)
#pragma unroll
      for (int n = 0; n < 4; ++n)
        acc[m][n] = __builtin_amdgcn_mfma_f32_16x16x32_bf16(
            Af[m], Bf[n], acc[m][n], 0, 0, 0);
    __syncthreads();
  }

  // ---- epilogue
  const int erow = (lane >> 4) * 4;
  const int ecol = lane & 15;
  if constexpr (MODE == 0) {
#pragma unroll
    for (int m = 0; m < 4; ++m)
#pragma unroll
      for (int n = 0; n < 4; ++n) {
        const size_t cb = n0 + wc * 64 + n * 16 + ecol;
#pragma unroll
        for (int j = 0; j < 4; ++j) {
          const size_t r = hrow0 + wr * 64 + m * 16 + erow + j;
          Gh[r * FDIM + cb] = __float2bfloat16(acc[m][n][j]);
        }
      }
  } else if constexpr (MODE == 1) {
#pragma unroll
    for (int m = 0; m < 4; ++m)
#pragma unroll
      for (int n = 0; n < 4; ++n) {
        const size_t cb = n0 + wc * 64 + n * 16 + ecol;
#pragma unroll
        for (int j = 0; j < 4; ++j) {
          const size_t r = hrow0 + wr * 64 + m * 16 + erow + j;
          const float g = __bfloat162float(Gh[r * FDIM + cb]);
          const float hv = g / (1.f + __expf(-g)) * acc[m][n][j];
          Gh[r * FDIM + cb] = __float2bfloat16(hv);
        }
      }
  } else {
#pragma unroll
    for (int m = 0; m < 4; ++m)
#pragma unroll
      for (int j = 0; j < 4; ++j) {
        const int i = mt * 128 + wr * 64 + m * 16 + erow + j;
        if (i < count) {
          const uint32_t info = (uint32_t)lst[i];
          const int tok = (int)(info & 0x7fffffffu);
          const float wt = ewts[e * N_TOK + i];
          float* prow = out + (size_t)tok * DIM;
#pragma unroll
          for (int n = 0; n < 4; ++n) {
            const int cb = n0 + wc * 64 + n * 16 + ecol;
            atomicAdd(prow + cb, wt * acc[m][n][j]);
          }
        }
      }
  }
}

extern "C" void kernel_launch(void* const* d_in, const int* in_sizes, int n_in,
                              void* d_out, int out_size, void* d_ws, size_t ws_size,
                              hipStream_t stream) {
  const float* stm = (const float*)d_in[0];
  const float* gw = (const float*)d_in[1];
  const float* w1 = (const float*)d_in[2];
  const float* w2 = (const float*)d_in[3];
  const float* w3 = (const float*)d_in[4];
  float* out = (float*)d_out;
  char* ws = (char*)d_ws;

  __hip_bfloat16* xb = (__hip_bfloat16*)(ws + XB_OFF);
  __hip_bfloat16* Gh = (__hip_bfloat16*)(ws + GH_OFF);
  int* cnt = (int*)(ws + CNT_OFF);
  int* ebase = (int*)(ws + EBASE_OFF);
  int* elist = (int*)(ws + ELIST_OFF);
  float* ewts = (float*)(ws + EWTS_OFF);
  __hip_bfloat16* wb = (__hip_bfloat16*)(ws + WB_OFF);

  zero_out_k<<<N_TOK * DIM / 1024, 256, 0, stream>>>(out);
  init_k<<<1, 64, 0, stream>>>(cnt);
  router_k<<<N_TOK, 256, 0, stream>>>(stm, gw, xb, cnt, elist, ewts);
  scan_k<<<1, 64, 0, stream>>>(cnt, ebase);

  const dim3 gUp(64, 16, 8);   // (Mtiles, panels/half, experts)
  const dim3 gDn(64, 8, 8);

  // gate GEMM (w1), two F-halves
  convW_k<<<2048, 256, 0, stream>>>(w1, wb, 0, 2048, FDIM, DIM);
  gemm128<DIM, 0><<<gUp, 256, 0, stream>>>(xb, wb, Gh, out, cnt, ebase, elist, ewts, 0);
  convW_k<<<2048, 256, 0, stream>>>(w1, wb, 2048, 2048, FDIM, DIM);
  gemm128<DIM, 0><<<gUp, 256, 0, stream>>>(xb, wb, Gh, out, cnt, ebase, elist, ewts, 2048);

  // up GEMM (w3) + silu*mul, two F-halves
  convW_k<<<2048, 256, 0, stream>>>(w3, wb, 0, 2048, FDIM, DIM);
  gemm128<DIM, 1><<<gUp, 256, 0, stream>>>(xb, wb, Gh, out, cnt, ebase, elist, ewts, 0);
  convW_k<<<2048, 256, 0, stream>>>(w3, wb, 2048, 2048, FDIM, DIM);
  gemm128<DIM, 1><<<gUp, 256, 0, stream>>>(xb, wb, Gh, out, cnt, ebase, elist, ewts, 2048);

  // down GEMM (w2), two D-halves
  convW_k<<<2048, 256, 0, stream>>>(w2, wb, 0, 1024, DIM, FDIM);
  gemm128<FDIM, 2><<<gDn, 256, 0, stream>>>(Gh, wb, Gh, out, cnt, ebase, elist, ewts, 0);
  convW_k<<<2048, 256, 0, stream>>>(w2, wb, 1024, 1024, DIM, FDIM);
  gemm128<FDIM, 2><<<gDn, 256, 0, stream>>>(Gh, wb, Gh, out, cnt, ebase, elist, ewts, 1024);
}

// Round 9
// 1595.283 us; speedup vs baseline: 2.4331x; 2.4331x over previous
//
#include <hip/hip_runtime.h>
#include <hip/hip_bf16.h>
#include <stdint.h>

#define N_TOK 8192
#define DIM   2048
#define FDIM  4096
#define NEXP  8

// ---- ws layout (bytes) ---- total EXACTLY 310,902,912 = round-1 proven floor
#define XB_OFF   0ull                        // bf16 x  [8192][2048]    33,554,432
#define HB_OFF   33554432ull                 // bf16 h  [17408][4096]  142,606,336
#define WB1_OFF  176160768ull                // bf16 w1/w2 half         67,108,864
#define WB3_OFF  243269632ull                // bf16 w3 half            67,108,864
#define META_OFF 310378496ull
#define CNT_OFF   (META_OFF)                 // int[8] (64B)
#define EBASE_OFF (META_OFF + 64ull)         // int[8] (64B)
#define ELIST_OFF (META_OFF + 128ull)        // int[8][8192]  262,144
#define EWTS_OFF  (ELIST_OFF + 262144ull)    // f32[8][8192]  262,144  -> end 310,902,912

typedef float f32x4 __attribute__((ext_vector_type(4)));
typedef short s16x8 __attribute__((ext_vector_type(8)));

__device__ __forceinline__ uint32_t pkbf(float a, float b) {
  uint32_t ua = __builtin_bit_cast(uint32_t, a) + 0x8000u;
  uint32_t ub = __builtin_bit_cast(uint32_t, b) + 0x8000u;
  return (ua >> 16) | (ub & 0xffff0000u);
}

__device__ __forceinline__ void gld16(const void* g, void* l) {
  __builtin_amdgcn_global_load_lds(
      (__attribute__((address_space(1))) void*)g,
      (__attribute__((address_space(3))) void*)l, 16, 0, 0);
}

__global__ void zero_out_k(float* out) {
  const size_t i = ((size_t)blockIdx.x * 256 + threadIdx.x) * 4;
  *(float4*)(out + i) = make_float4(0.f, 0.f, 0.f, 0.f);
}

__global__ void init_k(int* cnt) {
  if (threadIdx.x < NEXP) cnt[threadIdx.x] = 0;
}

__global__ void router_k(const float* __restrict__ x, const float* __restrict__ gw,
                         __hip_bfloat16* __restrict__ xb, int* __restrict__ cnt,
                         int* __restrict__ elist, float* __restrict__ ewts) {
  const int n = blockIdx.x;
  const int t = threadIdx.x;
  const float* xr = x + (size_t)n * DIM;
  const float4 v0 = *(const float4*)(xr + t * 8);
  const float4 v1 = *(const float4*)(xr + t * 8 + 4);
  uint4 u;
  u.x = pkbf(v0.x, v0.y); u.y = pkbf(v0.z, v0.w);
  u.z = pkbf(v1.x, v1.y); u.w = pkbf(v1.z, v1.w);
  *(uint4*)(xb + (size_t)n * DIM + t * 8) = u;

  float p[NEXP];
#pragma unroll
  for (int e = 0; e < NEXP; ++e) {
    const float* g = gw + e * DIM + t * 8;
    const float4 g0 = *(const float4*)g;
    const float4 g1 = *(const float4*)(g + 4);
    p[e] = v0.x * g0.x + v0.y * g0.y + v0.z * g0.z + v0.w * g0.w +
           v1.x * g1.x + v1.y * g1.y + v1.z * g1.z + v1.w * g1.w;
  }
#pragma unroll
  for (int off = 32; off >= 1; off >>= 1)
#pragma unroll
    for (int e = 0; e < NEXP; ++e) p[e] += __shfl_xor(p[e], off, 64);

  __shared__ float red[4][NEXP];
  const int lane = t & 63, wv = t >> 6;
  if (lane == 0) {
#pragma unroll
    for (int e = 0; e < NEXP; ++e) red[wv][e] = p[e];
  }
  __syncthreads();
  if (t == 0) {
    float l0 = -1e30f, l1 = -1e30f;
    int e0 = 0, e1 = 0;
#pragma unroll
    for (int e = 0; e < NEXP; ++e) {
      float v = red[0][e] + red[1][e] + red[2][e] + red[3][e];
      if (v > l0) { l1 = l0; e1 = e0; l0 = v; e0 = e; }
      else if (v > l1) { l1 = v; e1 = e; }
    }
    const float ed = expf(l1 - l0);
    const float inv = 1.f / (1.f + ed);
    int s0 = atomicAdd(cnt + e0, 1);
    elist[e0 * N_TOK + s0] = n;
    ewts[e0 * N_TOK + s0] = inv;
    int s1 = atomicAdd(cnt + e1, 1);
    elist[e1 * N_TOK + s1] = (int)((uint32_t)n | 0x80000000u);
    ewts[e1 * N_TOK + s1] = ed * inv;
  }
}

__global__ void scan_k(const int* __restrict__ cnt, int* __restrict__ ebase) {
  if (threadIdx.x == 0 && blockIdx.x == 0) {
    int b = 0;
    for (int e = 0; e < NEXP; ++e) { ebase[e] = b; b += (cnt[e] + 127) & ~127; }
  }
}

// convert rows [r0, r0+nrh) of each expert's [rtot][kd] fp32 matrix -> bf16 [e][nrh][kd]
__global__ void convW_k(const float* __restrict__ src, __hip_bfloat16* __restrict__ dst,
                        int r0, int nrh, int rtot, int kd) {
  const int cpr = kd / 8;
  const int total = NEXP * nrh * cpr;
  for (int i = blockIdx.x * blockDim.x + threadIdx.x; i < total;
       i += gridDim.x * blockDim.x) {
    const int e = i / (nrh * cpr);
    const int rem = i - e * nrh * cpr;
    const int lr = rem / cpr;
    const int c = rem - lr * cpr;
    const float* s = src + ((size_t)e * rtot + r0 + lr) * (size_t)kd + c * 8;
    const float4 a = *(const float4*)s;
    const float4 b = *(const float4*)(s + 4);
    uint4 u;
    u.x = pkbf(a.x, a.y); u.y = pkbf(a.z, a.w);
    u.z = pkbf(b.x, b.y); u.w = pkbf(b.z, b.w);
    *(uint4*)(dst + ((size_t)e * nrh + lr) * (size_t)kd + c * 8) = u;
  }
}

// ============================================================================
// Fused gate+up grouped GEMM (round-1 structure, PRE path): per 128x128 tile,
// h = silu(x@w1h^T) * (x@w3h^T) over one N-half. BK=32, 4 waves, 2-stage LDS
// dbuf, all three operands bf16 via global_load_lds w=16, plain 2-barrier
// K-loop (compiler-scheduled). LDS 48KB: A@0, B1@16384, B3@32768 (2x8KB each).
// Swizzle (both sides, rounds-5/8-verified): row r slot s holds src granule
// s^((r>>1)&3); read-side XOR is a per-lane constant -> 0 bank conflicts.
// ============================================================================
__global__ __launch_bounds__(256, 2) void moe_up_k(
    const __hip_bfloat16* __restrict__ xb, const __hip_bfloat16* __restrict__ w1b,
    const __hip_bfloat16* __restrict__ w3b, __hip_bfloat16* __restrict__ hb,
    const int* __restrict__ cnt, const int* __restrict__ ebase,
    const int* __restrict__ elist, int noff) {
  const int e = blockIdx.z;
  const int count = cnt[e];
  const int mt = blockIdx.y;
  if (mt * 128 >= count) return;
  const int bn0 = blockIdx.x * 128;          // col base within half
  const int ncol0 = noff + bn0;              // global F col base

  __shared__ char lds[49152];
  const int t = threadIdx.x;
  const int lane = t & 63, wv = t >> 6;
  const int wr = wv >> 1, wc = wv & 1;
  const int* lst = elist + e * N_TOK;
  const size_t hrow0 = (size_t)ebase[e] + (size_t)mt * 128;

  // ---- staging: thread (row r0 = t>>2, slot = t&3), chunks at rows r0, r0+64
  const int r0 = t >> 2;
  const int ks = (t & 3) ^ ((r0 >> 1) & 3);   // pre-swizzled source granule
  size_t sA[2], sB1[2], sB3[2];
  int ldsO[2];
#pragma unroll
  for (int i = 0; i < 2; ++i) {
    const int r = r0 + i * 64;
    int idx = mt * 128 + r;
    if (idx >= count) idx = 0;                 // clamp pad rows (finite values)
    const size_t tok = (size_t)(lst[idx] & 0x7fffffff);
    sA[i] = tok * DIM + ks * 8;
    sB1[i] = ((size_t)e * 2048 + bn0 + r) * DIM + ks * 8;
    sB3[i] = sB1[i];
    ldsO[i] = i * 4096 + wv * 1024;            // + lane*16 applied by HW
  }

  // ---- fragment read offsets (swizzle XOR is a per-lane constant)
  const int fr = lane & 15;
  const int swzc = ((lane >> 4) ^ ((fr >> 1) & 3)) << 4;
  const int aoff = (wr * 64 + fr) * 64 + swzc;           // + mi*1024
  const int boff = (wc * 64 + fr) * 64 + swzc;           // + ni*1024

  f32x4 accG[4][4], accU[4][4];
#pragma unroll
  for (int mi = 0; mi < 4; ++mi)
#pragma unroll
    for (int ni = 0; ni < 4; ++ni) {
      accG[mi][ni] = {0.f, 0.f, 0.f, 0.f};
      accU[mi][ni] = {0.f, 0.f, 0.f, 0.f};
    }

  auto stage = [&](int k0, int b) {
#pragma unroll
    for (int i = 0; i < 2; ++i)
      gld16(xb + sA[i] + k0, lds + b * 8192 + ldsO[i]);
#pragma unroll
    for (int i = 0; i < 2; ++i)
      gld16(w1b + sB1[i] + k0, lds + 16384 + b * 8192 + ldsO[i]);
#pragma unroll
    for (int i = 0; i < 2; ++i)
      gld16(w3b + sB3[i] + k0, lds + 32768 + b * 8192 + ldsO[i]);
  };

  stage(0, 0);
  __syncthreads();

  int b = 0;
  for (int kt = 0; kt < DIM / 32; ++kt) {
    const int nk = (kt + 1) * 32;
    if (nk < DIM) stage(nk, b ^ 1);
    s16x8 af[4], b1f[4], b3f[4];
#pragma unroll
    for (int mi = 0; mi < 4; ++mi)
      af[mi] = *(const s16x8*)(lds + b * 8192 + aoff + mi * 1024);
#pragma unroll
    for (int ni = 0; ni < 4; ++ni) {
      b1f[ni] = *(const s16x8*)(lds + 16384 + b * 8192 + boff + ni * 1024);
      b3f[ni] = *(const s16x8*)(lds + 32768 + b * 8192 + boff + ni * 1024);
    }
#pragma unroll
    for (int mi = 0; mi < 4; ++mi)
#pragma unroll
      for (int ni = 0; ni < 4; ++ni) {
        accG[mi][ni] = __builtin_amdgcn_mfma_f32_16x16x32_bf16(
            af[mi], b1f[ni], accG[mi][ni], 0, 0, 0);
        accU[mi][ni] = __builtin_amdgcn_mfma_f32_16x16x32_bf16(
            af[mi], b3f[ni], accU[mi][ni], 0, 0, 0);
      }
    __syncthreads();
    b ^= 1;
  }

  // ---- epilogue: h = silu(G)*U
  const int erow = (lane >> 4) * 4;
  const int ecol = lane & 15;
#pragma unroll
  for (int mi = 0; mi < 4; ++mi)
#pragma unroll
    for (int ni = 0; ni < 4; ++ni) {
      const size_t cb = ncol0 + wc * 64 + ni * 16 + ecol;
#pragma unroll
      for (int j = 0; j < 4; ++j) {
        const size_t r = hrow0 + wr * 64 + mi * 16 + erow + j;
        const float g = accG[mi][ni][j];
        const float uu = accU[mi][ni][j];
        const float h = g / (1.f + __expf(-g)) * uu;
        hb[r * FDIM + cb] = __float2bfloat16(h);
      }
    }
}

// ============================================================================
// Down grouped GEMM (round-1 structure, PRE path): out += we*(h@w2h^T) over
// one D-half. Same staging/swizzle; LDS 32KB; atomicAdd epilogue (each out
// element receives exactly 2 commutative fp32 adds -> deterministic).
// ============================================================================
__global__ __launch_bounds__(256, 2) void moe_down_k(
    const __hip_bfloat16* __restrict__ hb, const __hip_bfloat16* __restrict__ w2b,
    float* __restrict__ out, const int* __restrict__ cnt,
    const int* __restrict__ ebase, const int* __restrict__ elist,
    const float* __restrict__ ewts, int noff) {
  const int e = blockIdx.z;
  const int count = cnt[e];
  const int mt = blockIdx.y;
  if (mt * 128 >= count) return;
  const int bn0 = blockIdx.x * 128;
  const int ncol0 = noff + bn0;

  __shared__ char lds[32768];
  const int t = threadIdx.x;
  const int lane = t & 63, wv = t >> 6;
  const int wr = wv >> 1, wc = wv & 1;
  const int* lst = elist + e * N_TOK;
  const size_t hrow0 = (size_t)ebase[e] + (size_t)mt * 128;

  const int r0 = t >> 2;
  const int ks = (t & 3) ^ ((r0 >> 1) & 3);
  size_t sA[2], sB[2];
  int ldsO[2];
#pragma unroll
  for (int i = 0; i < 2; ++i) {
    const int r = r0 + i * 64;
    sA[i] = (hrow0 + r) * (size_t)FDIM + ks * 8;
    sB[i] = ((size_t)e * 1024 + bn0 + r) * (size_t)FDIM + ks * 8;
    ldsO[i] = i * 4096 + wv * 1024;
  }

  const int fr = lane & 15;
  const int swzc = ((lane >> 4) ^ ((fr >> 1) & 3)) << 4;
  const int aoff = (wr * 64 + fr) * 64 + swzc;
  const int boff = 16384 + (wc * 64 + fr) * 64 + swzc;

  f32x4 acc[4][4];
#pragma unroll
  for (int mi = 0; mi < 4; ++mi)
#pragma unroll
    for (int ni = 0; ni < 4; ++ni) acc[mi][ni] = {0.f, 0.f, 0.f, 0.f};

  auto stage = [&](int k0, int b) {
#pragma unroll
    for (int i = 0; i < 2; ++i)
      gld16(hb + sA[i] + k0, lds + b * 8192 + ldsO[i]);
#pragma unroll
    for (int i = 0; i < 2; ++i)
      gld16(w2b + sB[i] + k0, lds + 16384 + b * 8192 + ldsO[i]);
  };

  stage(0, 0);
  __syncthreads();

  int b = 0;
  for (int kt = 0; kt < FDIM / 32; ++kt) {
    const int nk = (kt + 1) * 32;
    if (nk < FDIM) stage(nk, b ^ 1);
    s16x8 af[4], bf[4];
#pragma unroll
    for (int mi = 0; mi < 4; ++mi)
      af[mi] = *(const s16x8*)(lds + b * 8192 + aoff + mi * 1024);
#pragma unroll
    for (int ni = 0; ni < 4; ++ni)
      bf[ni] = *(const s16x8*)(lds + b * 8192 + boff + ni * 1024);
#pragma unroll
    for (int mi = 0; mi < 4; ++mi)
#pragma unroll
      for (int ni = 0; ni < 4; ++ni)
        acc[mi][ni] = __builtin_amdgcn_mfma_f32_16x16x32_bf16(
            af[mi], bf[ni], acc[mi][ni], 0, 0, 0);
    __syncthreads();
    b ^= 1;
  }

  const int erow = (lane >> 4) * 4;
  const int ecol = lane & 15;
#pragma unroll
  for (int mi = 0; mi < 4; ++mi)
#pragma unroll
    for (int j = 0; j < 4; ++j) {
      const int i = mt * 128 + wr * 64 + mi * 16 + erow + j;
      if (i < count) {
        const uint32_t info = (uint32_t)lst[i];
        const int tok = (int)(info & 0x7fffffffu);
        const float wt = ewts[e * N_TOK + i];
        float* prow = out + (size_t)tok * DIM;
#pragma unroll
        for (int ni = 0; ni < 4; ++ni) {
          const int cb = ncol0 + wc * 64 + ni * 16 + ecol;
          atomicAdd(prow + cb, wt * acc[mi][ni][j]);
        }
      }
    }
}

extern "C" void kernel_launch(void* const* d_in, const int* in_sizes, int n_in,
                              void* d_out, int out_size, void* d_ws, size_t ws_size,
                              hipStream_t stream) {
  const float* stm = (const float*)d_in[0];
  const float* gw = (const float*)d_in[1];
  const float* w1 = (const float*)d_in[2];
  const float* w2 = (const float*)d_in[3];
  const float* w3 = (const float*)d_in[4];
  float* out = (float*)d_out;
  char* ws = (char*)d_ws;

  __hip_bfloat16* xb = (__hip_bfloat16*)(ws + XB_OFF);
  __hip_bfloat16* hb = (__hip_bfloat16*)(ws + HB_OFF);
  __hip_bfloat16* wb1 = (__hip_bfloat16*)(ws + WB1_OFF);
  __hip_bfloat16* wb3 = (__hip_bfloat16*)(ws + WB3_OFF);
  int* cnt = (int*)(ws + CNT_OFF);
  int* ebase = (int*)(ws + EBASE_OFF);
  int* elist = (int*)(ws + ELIST_OFF);
  float* ewts = (float*)(ws + EWTS_OFF);

  zero_out_k<<<N_TOK * DIM / 1024, 256, 0, stream>>>(out);
  init_k<<<1, 64, 0, stream>>>(cnt);
  router_k<<<N_TOK, 256, 0, stream>>>(stm, gw, xb, cnt, elist, ewts);
  scan_k<<<1, 64, 0, stream>>>(cnt, ebase);

  const dim3 gUp(16, 64, 8);   // (N-panels/half, M-tiles, experts)
  const dim3 gDn(8, 64, 8);

  // fused gate+up, F-half 0
  convW_k<<<2048, 256, 0, stream>>>(w1, wb1, 0, 2048, FDIM, DIM);
  convW_k<<<2048, 256, 0, stream>>>(w3, wb3, 0, 2048, FDIM, DIM);
  moe_up_k<<<gUp, 256, 0, stream>>>(xb, wb1, wb3, hb, cnt, ebase, elist, 0);
  // fused gate+up, F-half 1
  convW_k<<<2048, 256, 0, stream>>>(w1, wb1, 2048, 2048, FDIM, DIM);
  convW_k<<<2048, 256, 0, stream>>>(w3, wb3, 2048, 2048, FDIM, DIM);
  moe_up_k<<<gUp, 256, 0, stream>>>(xb, wb1, wb3, hb, cnt, ebase, elist, 2048);

  // down, D-half 0 and 1 (w2 half reuses wb1)
  convW_k<<<2048, 256, 0, stream>>>(w2, wb1, 0, 1024, DIM, FDIM);
  moe_down_k<<<gDn, 256, 0, stream>>>(hb, wb1, out, cnt, ebase, elist, ewts, 0);
  convW_k<<<2048, 256, 0, stream>>>(w2, wb1, 1024, 1024, DIM, FDIM);
  moe_down_k<<<gDn, 256, 0, stream>>>(hb, wb1, out, cnt, ebase, elist, ewts, 1024);
}